// Round 2
// baseline (1132.751 us; speedup 1.0000x reference)
//
#include <hip/hip_runtime.h>
#include <math.h>

#define N_NODES   50000
#define N_EDGES   800000
#define IN_FEAT   64
#define HIDDEN    32
#define GRID_SZ   4
#define N_GRAPHS  128
#define NEG_SLOPE 0.01f
#define NB        8      // nodes per block in KAN kernels

// ---------------------------------------------------------------------------
__global__ __launch_bounds__(256) void zero_kernel(float* __restrict__ p, int n) {
  const int i = blockIdx.x * 256 + threadIdx.x;
  if (i < n) p[i] = 0.f;
}

// ---------------------------------------------------------------------------
// h[n][o] = sum_{i,g} cos(x[n][i]*(g+1))*W0[o][i][g] + sin(...)*W1[o][i][g]
// W layout: (2, 32, 64, 4) flat.
// ---------------------------------------------------------------------------
__global__ __launch_bounds__(256) void kan_input_kernel(
    const float* __restrict__ X, const float* __restrict__ W,
    float* __restrict__ H) {
  __shared__ float cs[IN_FEAT * NB * GRID_SZ];  // [i][node][g], float4-friendly
  __shared__ float sn[IN_FEAT * NB * GRID_SZ];
  const int n0 = blockIdx.x * NB;
  const int tid = threadIdx.x;

  // phase 1: per-(node, i) sincos + angle-addition recurrence for k=1..4
  for (int idx = tid; idx < NB * IN_FEAT; idx += 256) {
    const int node = idx / IN_FEAT;
    const int i = idx % IN_FEAT;
    const float v = X[(n0 + node) * IN_FEAT + i];
    float s1, c1;
    sincosf(v, &s1, &c1);
    float c = c1, s = s1;
    const int base = (i * NB + node) * GRID_SZ;
    cs[base + 0] = c1; sn[base + 0] = s1;
#pragma unroll
    for (int g = 1; g < GRID_SZ; ++g) {
      const float cn = c * c1 - s * s1;
      const float sh = s * c1 + c * s1;
      c = cn; s = sh;
      cs[base + g] = c; sn[base + g] = s;
    }
  }
  __syncthreads();

  // phase 2: thread = (node = tid>>5, o = tid&31) -> coalesced H store
  const int o = tid & 31;
  const int node = tid >> 5;
  const float* __restrict__ W0 = W + o * (IN_FEAT * GRID_SZ);
  const float* __restrict__ W1 = W + HIDDEN * IN_FEAT * GRID_SZ + o * (IN_FEAT * GRID_SZ);
  float acc = 0.f;
#pragma unroll 4
  for (int i = 0; i < IN_FEAT; ++i) {
    const float4 cv = *reinterpret_cast<const float4*>(&cs[(i * NB + node) * GRID_SZ]);
    const float4 sv = *reinterpret_cast<const float4*>(&sn[(i * NB + node) * GRID_SZ]);
    const float4 w0 = *reinterpret_cast<const float4*>(&W0[i * GRID_SZ]);
    const float4 w1 = *reinterpret_cast<const float4*>(&W1[i * GRID_SZ]);
    acc += cv.x * w0.x + cv.y * w0.y + cv.z * w0.z + cv.w * w0.w;
    acc += sv.x * w1.x + sv.y * w1.y + sv.z * w1.z + sv.w * w1.w;
  }
  H[(n0 + node) * HIDDEN + o] = acc;
}

// ---------------------------------------------------------------------------
// t[n][o] = KAN(h[n]) with W_conv layer weights (2, 32, 32, 4) flat.
// ---------------------------------------------------------------------------
__global__ __launch_bounds__(256) void kan_node_kernel(
    const float* __restrict__ Hin, const float* __restrict__ W,
    float* __restrict__ T) {
  __shared__ float cs[HIDDEN * NB * GRID_SZ];  // [i][node][g]
  __shared__ float sn[HIDDEN * NB * GRID_SZ];
  const int n0 = blockIdx.x * NB;
  const int tid = threadIdx.x;

  {  // phase 1: exactly 256 (node, i) pairs
    const int node = tid / HIDDEN;
    const int i = tid % HIDDEN;
    const float v = Hin[(n0 + node) * HIDDEN + i];
    float s1, c1;
    sincosf(v, &s1, &c1);
    float c = c1, s = s1;
    const int base = (i * NB + node) * GRID_SZ;
    cs[base + 0] = c1; sn[base + 0] = s1;
#pragma unroll
    for (int g = 1; g < GRID_SZ; ++g) {
      const float cn = c * c1 - s * s1;
      const float sh = s * c1 + c * s1;
      c = cn; s = sh;
      cs[base + g] = c; sn[base + g] = s;
    }
  }
  __syncthreads();

  const int o = tid & 31;
  const int node = tid >> 5;
  const float* __restrict__ W0 = W + o * (HIDDEN * GRID_SZ);
  const float* __restrict__ W1 = W + HIDDEN * HIDDEN * GRID_SZ + o * (HIDDEN * GRID_SZ);
  float acc = 0.f;
#pragma unroll 4
  for (int i = 0; i < HIDDEN; ++i) {
    const float4 cv = *reinterpret_cast<const float4*>(&cs[(i * NB + node) * GRID_SZ]);
    const float4 sv = *reinterpret_cast<const float4*>(&sn[(i * NB + node) * GRID_SZ]);
    const float4 w0 = *reinterpret_cast<const float4*>(&W0[i * GRID_SZ]);
    const float4 w1 = *reinterpret_cast<const float4*>(&W1[i * GRID_SZ]);
    acc += cv.x * w0.x + cv.y * w0.y + cv.z * w0.z + cv.w * w0.w;
    acc += sv.x * w1.x + sv.y * w1.y + sv.z * w1.z + sv.w * w1.w;
  }
  T[(n0 + node) * HIDDEN + o] = acc;
}

// ---------------------------------------------------------------------------
// m[dst[e]][f] += t[src[e]][f]   (32 threads per edge)
// ---------------------------------------------------------------------------
__global__ __launch_bounds__(256) void edge_scatter_kernel(
    const float* __restrict__ T, const int* __restrict__ src,
    const int* __restrict__ dst, float* __restrict__ M) {
  const int gid = blockIdx.x * 256 + threadIdx.x;
  const int e = gid >> 5;
  const int f = gid & 31;
  if (e < N_EDGES) {
    const int s = src[e];
    const int d = dst[e];
    atomicAdd(&M[d * HIDDEN + f], T[s * HIDDEN + f]);
  }
}

// ---------------------------------------------------------------------------
// h = leaky_relu(m + h)
// ---------------------------------------------------------------------------
__global__ __launch_bounds__(256) void update_kernel(
    float* __restrict__ H, const float* __restrict__ M) {
  const int i = blockIdx.x * 256 + threadIdx.x;
  if (i < N_NODES * HIDDEN) {
    const float v = M[i] + H[i];
    H[i] = (v >= 0.f) ? v : NEG_SLOPE * v;
  }
}

// ---------------------------------------------------------------------------
// per-graph sums + counts
// ---------------------------------------------------------------------------
__global__ __launch_bounds__(256) void pool_kernel(
    const float* __restrict__ H, const int* __restrict__ batch,
    float* __restrict__ sums, float* __restrict__ cnt) {
  const int gid = blockIdx.x * 256 + threadIdx.x;
  const int n = gid >> 5;
  const int f = gid & 31;
  if (n < N_NODES) {
    const int g = batch[n];
    atomicAdd(&sums[g * HIDDEN + f], H[n * HIDDEN + f]);
    if (f == 0) atomicAdd(&cnt[g], 1.0f);
  }
}

// ---------------------------------------------------------------------------
// readout: y = sums/max(cnt,1); out = sigmoid(cos(y).W0 + sin(y).W1 + b)
// W_out: (2, 1, 32, 1) flat -> W0 = [0..31], W1 = [32..63]
// ---------------------------------------------------------------------------
__global__ __launch_bounds__(128) void readout_kernel(
    const float* __restrict__ sums, const float* __restrict__ cnt,
    const float* __restrict__ Wout, const float* __restrict__ bout,
    float* __restrict__ out) {
  const int g = threadIdx.x;
  if (g < N_GRAPHS) {
    const float c = fmaxf(cnt[g], 1.0f);
    float z = 0.f;
#pragma unroll
    for (int i = 0; i < HIDDEN; ++i) {
      const float y = sums[g * HIDDEN + i] / c;
      z += cosf(y) * Wout[i] + sinf(y) * Wout[HIDDEN + i];
    }
    z += bout[0];
    out[g] = 1.0f / (1.0f + expf(-z));
  }
}

// ---------------------------------------------------------------------------
extern "C" void kernel_launch(void* const* d_in, const int* in_sizes, int n_in,
                              void* d_out, int out_size, void* d_ws, size_t ws_size,
                              hipStream_t stream) {
  const float* x        = (const float*)d_in[0];
  const int*   eidx     = (const int*)d_in[1];    // int32 per harness convention
  const int*   batch    = (const int*)d_in[2];    // int32 per harness convention
  const float* W_in     = (const float*)d_in[3];
  const float* W_conv   = (const float*)d_in[4];
  const float* W_out    = (const float*)d_in[5];
  const float* b_out    = (const float*)d_in[6];
  float* out            = (float*)d_out;

  const int* src = eidx;            // edge_index[0]
  const int* dst = eidx + N_EDGES;  // edge_index[1]

  float* ws = (float*)d_ws;
  float* H    = ws;                       // 1.6M floats
  float* T    = ws + 1600000;             // 1.6M floats
  float* M    = ws + 3200000;             // 1.6M floats
  float* SUMS = ws + 4800000;             // 4096 floats
  float* CNT  = ws + 4804096;             // 128 floats

  const int kan_blocks  = N_NODES / NB;              // 6250
  const int edge_blocks = (N_EDGES * 32) / 256;      // 100000
  const int elem_blocks = (N_NODES * HIDDEN) / 256;  // 6250

  // input KAN projection
  kan_input_kernel<<<kan_blocks, 256, 0, stream>>>(x, W_in, H);

  const int WCONV_STRIDE = 2 * HIDDEN * HIDDEN * GRID_SZ;  // 8192
  for (int l = 0; l < 2; ++l) {
    kan_node_kernel<<<kan_blocks, 256, 0, stream>>>(H, W_conv + l * WCONV_STRIDE, T);
    zero_kernel<<<elem_blocks, 256, 0, stream>>>(M, N_NODES * HIDDEN);
    edge_scatter_kernel<<<edge_blocks, 256, 0, stream>>>(T, src, dst, M);
    update_kernel<<<elem_blocks, 256, 0, stream>>>(H, M);
  }

  zero_kernel<<<17, 256, 0, stream>>>(SUMS, N_GRAPHS * HIDDEN + N_GRAPHS);
  pool_kernel<<<elem_blocks, 256, 0, stream>>>(H, batch, SUMS, CNT);
  readout_kernel<<<1, 128, 0, stream>>>(SUMS, CNT, W_out, b_out, out);
}